// Round 3
// baseline (79.786 us; speedup 1.0000x reference)
//
#include <hip/hip_runtime.h>
#include <math.h>

// R10 = R7 kernel source VERBATIM (the 63.28us best; R8/R9 restructures both
// regressed and are reverted), launched 3x back-to-back as a TIMING
// DECOMPOSITION EXPERIMENT. The kernel is a pure function of (Y,Z,R) writing
// only `out`, so repeated launches are graph-safe and output-identical.
//   dur_us = floor + 3*K  (R7: floor + K = 63.3)  =>  K = (dur_us - 63.3)/2
// This resolves whether the kernel is ~22us (serial-phase-bound, big
// headroom) or ~3-8us (dur_us dominated by the harness's 256MiB poison
// fill, which already runs at the HBM roofline).

#define D_DIM 256
#define K_DIM 128
#define ZS    260   // z row stride (floats): bank-quad (k + c) mod 32 -> 2-way, free
#define ROWS  8

__global__ __launch_bounds__(1024) void hyp_mlr_kernel(
    const float* __restrict__ Y,   // (2048,256)
    const float* __restrict__ Z,   // (128,256)
    const float* __restrict__ R,   // (128,1)
    float* __restrict__ out)       // (2048,128)
{
  __shared__ float zt[K_DIM * ZS];           // 133,120 B: full Z, padded rows
  __shared__ float part4[4 * K_DIM * 2 * 4]; // 16,384 B: [q][k][half] float4 accs
  __shared__ float nzq[4 * K_DIM];           //  2,048 B: [q][k] nz2 partials
  __shared__ float sy2[ROWS];

  const int t    = threadIdx.x;
  const int lane = t & 63;
  const int wv   = __builtin_amdgcn_readfirstlane(threadIdx.x >> 6); // 0..15
  const int qd   = (wv >> 1) & 3;            // uniform d-quarter
  const int h    = wv >> 3;                  // uniform row-half
  const int k    = lane + ((wv & 1) << 6);   // 0..127
  const int b0   = blockIdx.x * ROWS;
  const float* __restrict__ yb = Y + (size_t)b0 * D_DIM;  // block-uniform

  // ---- stage full Z -> LDS, coalesced: 8192 float4, 8 per thread ----
  #pragma unroll
  for (int i = 0; i < 8; ++i) {
    int idx = t + i * 1024;
    int r = idx >> 6, q = idx & 63;
    float4 v = *(const float4*)(Z + r * D_DIM + q * 4);
    *(float4*)&zt[r * ZS + q * 4] = v;
  }

  // ---- y2: waves 0..7 own row wv (coalesced + 64-lane butterfly) ----
  if (wv < ROWS) {
    const float* yr = yb + wv * D_DIM;
    float4 u = *(const float4*)(yr + lane * 4);
    float s = u.x*u.x + u.y*u.y + u.z*u.z + u.w*u.w;
    #pragma unroll
    for (int off = 32; off > 0; off >>= 1) s += __shfl_xor(s, off);
    if (lane == 0) sy2[wv] = s;
  }

  __syncthreads();

  // ---- main: 4 rows x 1 k x 64 d, two 32-float sub-chunks ----
  float acc[4] = {0.f, 0.f, 0.f, 0.f};
  float nzp = 0.f;
  const float* zp = &zt[k * ZS + qd * 64];
  const float* yq = yb + qd * 64 + h * 4 * D_DIM;
  #pragma unroll
  for (int sub = 0; sub < 2; ++sub) {
    float4 zr[8];
    #pragma unroll
    for (int i = 0; i < 8; ++i) zr[i] = *(const float4*)(zp + sub * 32 + 4 * i);
    #pragma unroll
    for (int i = 0; i < 8; ++i) {
      nzp = fmaf(zr[i].x, zr[i].x, nzp); nzp = fmaf(zr[i].y, zr[i].y, nzp);
      nzp = fmaf(zr[i].z, zr[i].z, nzp); nzp = fmaf(zr[i].w, zr[i].w, nzp);
    }
    #pragma unroll
    for (int r = 0; r < 4; ++r) {
      const float* yr = yq + r * D_DIM + sub * 32;
      float a = acc[r];
      #pragma unroll
      for (int i = 0; i < 8; ++i) {
        float4 yv = *(const float4*)(yr + 4 * i);   // uniform -> scalar cache
        a = fmaf(yv.x, zr[i].x, a);
        a = fmaf(yv.y, zr[i].y, a);
        a = fmaf(yv.z, zr[i].z, a);
        a = fmaf(yv.w, zr[i].w, a);
      }
      acc[r] = a;
    }
  }

  // ---- export partials: one b128 per thread; nz2 once per (q,k) ----
  *(float4*)&part4[(((qd * K_DIM + k) * 2 + h) << 2)] =
      make_float4(acc[0], acc[1], acc[2], acc[3]);
  if (h == 0) nzq[qd * K_DIM + k] = nzp;
  __syncthreads();

  // ---- flat epilogue: thread -> one (row, k) output element ----
  {
    const int ke  = t & 127;
    const int row = t >> 7;               // 0..7
    const int hh  = row >> 2, rr = row & 3;
    float a = 0.f, nz2 = 0.f;
    #pragma unroll
    for (int q = 0; q < 4; ++q) {
      a   += part4[(((q * K_DIM + ke) * 2 + hh) << 2) + rr];
      nz2 += nzq[q * K_DIM + ke];
    }
    float nz = sqrtf(nz2);
    float rv = R[ke];                     // lane->ke consecutive: coalesced
    float un = fmaxf(fabsf(rv) * nz, 1e-15f);   // EPS clamp, matches ref
    float ts = copysignf(tanhf(un), rv);
    float ch = coshf(rv);
    float inv_nz = 1.f / fmaxf(nz, 1e-30f);
    float an2 = 2.f * nz / (ch * ch);
    float x2 = ts * ts;
    float w  = a * inv_nz;                // y . a_hat
    float y2 = sy2[row];
    float xy = -ts * w;
    float A   = 1.f + 2.f * xy + y2;
    float Bc  = 1.f - x2;
    float den = 1.f + 2.f * xy + x2 * y2;
    float invden = 1.f / den;
    float mm  = (A*A*x2 + 2.f*A*Bc*xy + Bc*Bc*y2) * invden * invden;
    float lam = 2.f / (1.f - mm);
    float ma  = (Bc * w - A * ts) * invden;     // m . a_hat
    out[(b0 + row) * K_DIM + ke] = an2 * asinhf(ma * lam);
  }
}

extern "C" void kernel_launch(void* const* d_in, const int* in_sizes, int n_in,
                              void* d_out, int out_size, void* d_ws, size_t ws_size,
                              hipStream_t stream) {
  const float* Y = (const float*)d_in[0];
  const float* Z = (const float*)d_in[1];
  const float* R = (const float*)d_in[2];
  float* out = (float*)d_out;
  // 3x launch: timing decomposition (see header comment). Idempotent.
  hipLaunchKernelGGL(hyp_mlr_kernel, dim3(2048 / ROWS), dim3(1024), 0, stream,
                     Y, Z, R, out);
  hipLaunchKernelGGL(hyp_mlr_kernel, dim3(2048 / ROWS), dim3(1024), 0, stream,
                     Y, Z, R, out);
  hipLaunchKernelGGL(hyp_mlr_kernel, dim3(2048 / ROWS), dim3(1024), 0, stream,
                     Y, Z, R, out);
}

// Round 4
// 62.131 us; speedup vs baseline: 1.2842x; 1.2842x over previous
//
#include <hip/hip_runtime.h>
#include <math.h>

// Hyp_plus_MLR closed form (all reductions along a_hat = z_k/||z_k||):
//   ts=sign(r)tanh(|r|*||z||), an2=2||z||/cosh^2 r, w=(y.z)/||z||
//   xy=-ts*w, x2=ts^2, A=1+2xy+y2, Bc=1-x2, den=1+2xy+x2*y2
//   P=A^2 x2+2ABc xy+Bc^2 y2, ma*lam = 2(Bc w-A ts)*den/(den^2-P)
//   out[b,k] = an2 * asinh(ma*lam)
//
// R10 decomposition: kernel K ~= 8.25us warm, harness floor ~= 55us
// (41us roofline-saturated poison fill + resets). Work content ~2-3us;
// the gap is latency exposure at 1 block/CU.
//
// R7 -> R11 (geometry FROZEN: 256 blocks x 1024 thr, same LDS, same
// lane->(k,qd,h) mapping; R8/R9 proved geometry changes regress):
//  1. All 16 z ds_read_b128 hoisted to loop top (zr[16], ~90 VGPR, same
//     occupancy tier). SMEM (y s_loads) and DS (z) both count lgkmcnt and
//     SMEM returns out-of-order -> mixing them forces repeated lgkmcnt(0)
//     full drains, serially exposing each y-chunk's ~200cy L2 latency.
//     With z done in one early drain, y s_load chunks overlap pure FMA.
//  2. nzp FMAs only in the h==0 half (h==1's result was discarded).
//  3. R staged to LDS in phase 0 (kills the post-barrier cold-HBM tail
//     stall on R[ke]; component validated in R8/R9).
//  4. Cheap epilogue (exp-based tanh/sech^2, rcp+NR, __logf asinh) --
//     validated twice at identical absmax 0.00390625, ~3x shorter chain.

#define D_DIM 256
#define K_DIM 128
#define ZS    260   // z row stride (floats): bank-quad (k + c) mod 32 -> 2-way, free
#define ROWS  8

__global__ __launch_bounds__(1024) void hyp_mlr_kernel(
    const float* __restrict__ Y,   // (2048,256)
    const float* __restrict__ Z,   // (128,256)
    const float* __restrict__ R,   // (128,1)
    float* __restrict__ out)       // (2048,128)
{
  __shared__ float zt[K_DIM * ZS];           // 133,120 B: full Z, padded rows
  __shared__ float part4[4 * K_DIM * 2 * 4]; // 16,384 B: [q][k][half] float4 accs
  __shared__ float nzq[4 * K_DIM];           //  2,048 B: [q][k] nz2 partials
  __shared__ float sy2[ROWS];
  __shared__ float rld[K_DIM];               //    512 B: staged R

  const int t    = threadIdx.x;
  const int lane = t & 63;
  const int wv   = __builtin_amdgcn_readfirstlane(threadIdx.x >> 6); // 0..15
  const int qd   = (wv >> 1) & 3;            // uniform d-quarter
  const int h    = wv >> 3;                  // uniform row-half
  const int k    = lane + ((wv & 1) << 6);   // 0..127
  const int b0   = blockIdx.x * ROWS;
  const float* __restrict__ yb = Y + (size_t)b0 * D_DIM;  // block-uniform

  // ---- stage full Z -> LDS, coalesced: 8192 float4, 8 per thread ----
  #pragma unroll
  for (int i = 0; i < 8; ++i) {
    int idx = t + i * 1024;
    int r = idx >> 6, q = idx & 63;
    float4 v = *(const float4*)(Z + r * D_DIM + q * 4);
    *(float4*)&zt[r * ZS + q * 4] = v;
  }
  if (t < K_DIM) rld[t] = R[t];

  // ---- y2: waves 0..7 own row wv (coalesced + 64-lane butterfly) ----
  if (wv < ROWS) {
    const float* yr = yb + wv * D_DIM;
    float4 u = *(const float4*)(yr + lane * 4);
    float s = u.x*u.x + u.y*u.y + u.z*u.z + u.w*u.w;
    #pragma unroll
    for (int off = 32; off > 0; off >>= 1) s += __shfl_xor(s, off);
    if (lane == 0) sy2[wv] = s;
  }

  __syncthreads();

  // ---- main: 4 rows x 1 k x 64 d; z fully hoisted to regs first ----
  float acc[4] = {0.f, 0.f, 0.f, 0.f};
  float nzp = 0.f;
  const float* zp = &zt[k * ZS + qd * 64];
  const float* yq = yb + qd * 64 + h * 4 * D_DIM;
  float4 zr[16];
  #pragma unroll
  for (int i = 0; i < 16; ++i) zr[i] = *(const float4*)(zp + 4 * i);
  if (h == 0) {                              // wave-uniform; h==1 discarded it
    #pragma unroll
    for (int i = 0; i < 16; ++i) {
      nzp = fmaf(zr[i].x, zr[i].x, nzp); nzp = fmaf(zr[i].y, zr[i].y, nzp);
      nzp = fmaf(zr[i].z, zr[i].z, nzp); nzp = fmaf(zr[i].w, zr[i].w, nzp);
    }
  }
  #pragma unroll
  for (int r = 0; r < 4; ++r) {
    const float* yr = yq + r * D_DIM;
    float a = acc[r];
    #pragma unroll
    for (int i = 0; i < 16; ++i) {
      float4 yv = *(const float4*)(yr + 4 * i);     // uniform -> scalar pipe
      a = fmaf(yv.x, zr[i].x, a);
      a = fmaf(yv.y, zr[i].y, a);
      a = fmaf(yv.z, zr[i].z, a);
      a = fmaf(yv.w, zr[i].w, a);
    }
    acc[r] = a;
  }

  // ---- export partials: one b128 per thread; nz2 once per (q,k) ----
  *(float4*)&part4[(((qd * K_DIM + k) * 2 + h) << 2)] =
      make_float4(acc[0], acc[1], acc[2], acc[3]);
  if (h == 0) nzq[qd * K_DIM + k] = nzp;
  __syncthreads();

  // ---- flat epilogue: thread -> one (row, k) output element ----
  {
    const int ke  = t & 127;
    const int row = t >> 7;               // 0..7
    const int hh  = row >> 2, rr = row & 3;
    float a = 0.f, nz2 = 0.f;
    #pragma unroll
    for (int q = 0; q < 4; ++q) {
      a   += part4[(((q * K_DIM + ke) * 2 + hh) << 2) + rr];
      nz2 += nzq[q * K_DIM + ke];
    }
    float rv = rld[ke];                   // LDS: staged in phase 0
    float y2 = sy2[row];
    float nz = sqrtf(nz2);
    float ar = fabsf(rv);
    float un = fmaxf(ar * nz, 1e-15f);    // EPS clamp, matches ref
    // tanh(un) = 1 - 2e/(1+e), e = exp(-2un)
    float te = __expf(-2.f * un);
    float d1 = 1.f + te;
    float r1 = __builtin_amdgcn_rcpf(d1); r1 = r1 * (2.f - d1 * r1);
    float ts = copysignf(1.f - 2.f * te * r1, rv);
    // sech^2(rv) = 4u/(1+u)^2, u = exp(-2|rv|)
    float ue = __expf(-2.f * ar);
    float d2 = 1.f + ue;
    float r2 = __builtin_amdgcn_rcpf(d2); r2 = r2 * (2.f - d2 * r2);
    float an2 = 2.f * nz * (4.f * ue * r2 * r2);
    float nzc = fmaxf(nz, 1e-30f);
    float ri  = __builtin_amdgcn_rcpf(nzc); ri = ri * (2.f - nzc * ri);
    float x2  = ts * ts;
    float w   = a * ri;                   // y . a_hat
    float xy  = -ts * w;
    float s   = fmaf(2.f, xy, 1.f);       // 1 + 2xy
    float A   = s + y2;
    float Bc  = 1.f - x2;
    float den = fmaf(x2, y2, s);
    float P   = fmaf(A, fmaf(x2, A, 2.f * Bc * xy), Bc * Bc * y2);
    float d   = fmaf(den, den, -P);       // den^2 - P = den^2 (1 - |m|^2)
    float qn  = 2.f * fmaf(Bc, w, -(A * ts)) * den;
    float r0  = __builtin_amdgcn_rcpf(d); r0 = r0 * (2.f - d * r0);
    float v   = qn * r0;                  // ma * lam
    float sv  = fabsf(v);
    float t2  = sqrtf(fmaf(sv, sv, 1.f));
    float res = an2 * __logf(sv + t2);    // an2 * asinh(|v|)
    out[(size_t)(b0 + row) * K_DIM + ke] = copysignf(res, v);
  }
}

extern "C" void kernel_launch(void* const* d_in, const int* in_sizes, int n_in,
                              void* d_out, int out_size, void* d_ws, size_t ws_size,
                              hipStream_t stream) {
  const float* Y = (const float*)d_in[0];
  const float* Z = (const float*)d_in[1];
  const float* R = (const float*)d_in[2];
  float* out = (float*)d_out;
  hipLaunchKernelGGL(hyp_mlr_kernel, dim3(2048 / ROWS), dim3(1024), 0, stream,
                     Y, Z, R, out);
}